// Round 11
// baseline (233.037 us; speedup 1.0000x reference)
//
#include <hip/hip_runtime.h>
#include <hip/hip_bf16.h>

// RandScatter with a CONSTANT score matrix:
//   route = argmax(score, axis=1) = [0, 1, 1, 1]
//   out = concat(inputs[[0]], inputs[[1,2,3]]) = inputs, verbatim.
// Pure 128 MiB fp32 D2D copy, memory-bound.
//
// History (copy-dispatch time; bench overhead is a constant ~150 us):
//  R2:  hipMemcpyAsync under capture -> SDMA path, slow.
//  R6:  cached float4 grid-stride:        81.4 us (~3.3 TB/s combined)
//  R7:  cached x8 unroll:                 90   us (confounded by cache churn)
//  R8:  NT load + NT store, no unroll:   ~68   us  <- best so far
//  R10: cached load + NT store:           79.9 us (cached reads HURT)
//  R11 theory: R8 is issue-rate-bound — VGPR=8 means ONE dependent
//    load->store chain per wave. NT + x8 unroll = 8 independent NT loads
//    in flight per wave (8 KB MLP), then 8 NT stores. Target ~43-55 us.

typedef float f4 __attribute__((ext_vector_type(4)));

__global__ __launch_bounds__(256) void copy_nt8_kernel(
    const f4* __restrict__ src, f4* __restrict__ dst, long n4) {
    long nt  = (long)gridDim.x * blockDim.x;   // total threads
    long i   = (long)blockIdx.x * blockDim.x + threadIdx.x;
    for (; i + 7 * nt < n4; i += 8 * nt) {
        f4 a0 = __builtin_nontemporal_load(src + i);
        f4 a1 = __builtin_nontemporal_load(src + i + nt);
        f4 a2 = __builtin_nontemporal_load(src + i + 2 * nt);
        f4 a3 = __builtin_nontemporal_load(src + i + 3 * nt);
        f4 a4 = __builtin_nontemporal_load(src + i + 4 * nt);
        f4 a5 = __builtin_nontemporal_load(src + i + 5 * nt);
        f4 a6 = __builtin_nontemporal_load(src + i + 6 * nt);
        f4 a7 = __builtin_nontemporal_load(src + i + 7 * nt);
        __builtin_nontemporal_store(a0, dst + i);
        __builtin_nontemporal_store(a1, dst + i + nt);
        __builtin_nontemporal_store(a2, dst + i + 2 * nt);
        __builtin_nontemporal_store(a3, dst + i + 3 * nt);
        __builtin_nontemporal_store(a4, dst + i + 4 * nt);
        __builtin_nontemporal_store(a5, dst + i + 5 * nt);
        __builtin_nontemporal_store(a6, dst + i + 6 * nt);
        __builtin_nontemporal_store(a7, dst + i + 7 * nt);
    }
    for (; i < n4; i += nt) {   // tail: empty for this shape
        f4 v = __builtin_nontemporal_load(src + i);
        __builtin_nontemporal_store(v, dst + i);
    }
}

extern "C" void kernel_launch(void* const* d_in, const int* in_sizes, int n_in,
                              void* d_out, int out_size, void* d_ws, size_t ws_size,
                              hipStream_t stream) {
    (void)n_in; (void)d_ws; (void)ws_size; (void)in_sizes;
    const f4* in = (const f4*)d_in[0];
    f4* out = (f4*)d_out;
    long n4 = (long)out_size / 4;   // 8388608 float4s
    const int block = 256;
    const int grid = 2048;          // 524288 threads -> exactly 2 unrolled iters
    copy_nt8_kernel<<<grid, block, 0, stream>>>(in, out, n4);
}